// Round 4
// baseline (2463.806 us; speedup 1.0000x reference)
//
#include <hip/hip_runtime.h>
#include <hip/hip_bf16.h>

#define NSTEPS 10
#define DT     0.1f
#define LNEPS  1e-5f
#define NLOG2E (-1.4426950408889634f)

typedef __attribute__((ext_vector_type(8))) short v8s;   // 8 bf16 MFMA operand
typedef __attribute__((ext_vector_type(4))) float v4f;   // 4 fp32 MFMA accum

static __device__ __forceinline__ ushort f2bf(float f) {
  union { float f; unsigned u; } v; v.f = f;
  unsigned r = v.u + 0x7fffu + ((v.u >> 16) & 1u);   // RNE
  return (ushort)(r >> 16);
}
static __device__ __forceinline__ float bfl(unsigned u) {
  union { unsigned x; float f; } c; c.x = u << 16; return c.f;
}
static __device__ __forceinline__ float bfh(unsigned u) {
  union { unsigned x; float f; } c; c.x = u & 0xffff0000u; return c.f;
}
static __device__ __forceinline__ unsigned pk2(float a, float b) {
  union { __hip_bfloat162 h; unsigned u; } c;
  c.h = __float22bfloat162_rn(make_float2(a, b));   // v_cvt_pk_bf16_f32
  return c.u;
}

// ---------------------------------------------------------------------------
// Pack W into MFMA **A-fragment** order (operand-swapped GEMM: D = W · h^T).
// A[i][k]: frag f = (kc*NT + nt)*64 + lane; lane=(q,m): value = W_A[nt*16+m][kc*32+q*8+j].
// direct==1: W_A[n][k] = src[n*K + k] (*msk)   (W_rec masked, out_W)
// direct==0: W_A[n][k] = src[k*N + n]          (W_in)
// ---------------------------------------------------------------------------
__global__ void pack_wA(const float* __restrict__ src, const float* __restrict__ msk,
                        ushort* __restrict__ dst, int K, int N, int direct, float scale) {
  int ntc = N >> 4;
  int tot = (K >> 5) * ntc * 64;
  int f = blockIdx.x * blockDim.x + threadIdx.x;
  if (f >= tot) return;
  int lf = f & 63;
  int rest = f >> 6;
  int nt = rest % ntc;
  int kc = rest / ntc;
  int n = nt * 16 + (lf & 15);
  int kb = kc * 32 + (lf >> 4) * 8;
  ushort v[8];
#pragma unroll
  for (int j = 0; j < 8; ++j) {
    int k = kb + j;
    float s;
    if (direct) {
      s = src[(size_t)n * K + k];
      if (msk) s *= msk[(size_t)n * K + k];
    } else {
      s = src[(size_t)k * N + n];
    }
    v[j] = f2bf(s * scale);
  }
  uint4 u;
  u.x = (unsigned)v[0] | ((unsigned)v[1] << 16);
  u.y = (unsigned)v[2] | ((unsigned)v[3] << 16);
  u.z = (unsigned)v[4] | ((unsigned)v[5] << 16);
  u.w = (unsigned)v[6] | ((unsigned)v[7] << 16);
  *(uint4*)(dst + (size_t)f * 8) = u;
}

// Planar per-col constants: cA = dt*A, cC1 = 1+dt/tau, cG = g, cB = b.
__global__ void pack_consts(const float* __restrict__ tau, const float* __restrict__ A,
                            const float* __restrict__ g, const float* __restrict__ b,
                            float* __restrict__ cA, float* __restrict__ cC1,
                            float* __restrict__ cG, float* __restrict__ cB) {
  int c = blockIdx.x * blockDim.x + threadIdx.x;
  if (c >= 512) return;
  cA[c] = DT * A[c];
  cC1[c] = 1.f + DT / tau[c];
  cG[c] = g[c];
  cB[c] = b[c];
}

struct LayerG {
  const ushort* win;
  const ushort* wrec;
  const float*  bias;   // raw f32, scaled by -log2e at base build
  const float*  cA, *cC1, *cG, *cB;
};
struct KP {
  const float* x;
  LayerG L[3];
  const ushort* wout;
  const float*  outb;
  float* out;
};

// ---------------------------------------------------------------------------
// Operand-swapped GEMM: acc[nt][bt] = W_slab · h^T.
// A (weights) streamed from global (L2), 2-deep prefetch.
// B (h) read from fragment-ordered LDS: lane-contiguous ds_read_b128.
// D C-layout: n = (wv*4+nt)*16 + q*4 + r,  batchrow = bt*16 + m.
// ---------------------------------------------------------------------------
template <int KC>
static __device__ __forceinline__ void gemmA(const ushort* hb, const ushort* __restrict__ w,
                                             int wb, int lane, v4f (&acc)[4][4]) {
#pragma unroll
  for (int nt = 0; nt < 4; ++nt)
#pragma unroll
    for (int bt = 0; bt < 4; ++bt) acc[nt][bt] = (v4f){0.f, 0.f, 0.f, 0.f};
  v8s a0[4], a1[4];
  auto ldA = [&](v8s (&a)[4], int kc) {
#pragma unroll
    for (int nt = 0; nt < 4; ++nt)
      a[nt] = *(const v8s*)(w + ((size_t)(kc * 32 + wb + nt) * 64 + lane) * 8);
  };
  auto body = [&](v8s (&a)[4], int kc) {
    v8s b[4];
#pragma unroll
    for (int bt = 0; bt < 4; ++bt)
      b[bt] = *(const v8s*)(hb + ((size_t)(kc * 4 + bt) * 64 + lane) * 8);
#pragma unroll
    for (int nt = 0; nt < 4; ++nt)
#pragma unroll
      for (int bt = 0; bt < 4; ++bt)
        acc[nt][bt] = __builtin_amdgcn_mfma_f32_16x16x32_bf16(a[nt], b[bt], acc[nt][bt], 0, 0, 0);
    if (kc + 2 < KC) ldA(a, kc + 2);
  };
  ldA(a0, 0);
  ldA(a1, 1);
#pragma unroll
  for (int kc = 0; kc < KC; kc += 2) {
    body(a0, kc);
    body(a1, kc + 1);
  }
}

// ---------------------------------------------------------------------------
// Fused kernel: 512 thr (8 waves), 64 rows/block, grid 512 (2 rounds/CU).
// h lives in LDS in B-fragment order; 2 barriers/step; no transposes.
// ---------------------------------------------------------------------------
__global__ __launch_bounds__(512, 2) void liquid_fused(KP P) {
  extern __shared__ char smem[];
  ushort* hb = (ushort*)smem;                 // 16kc x 4bt x 64lane x 8 = 64 KB
  float2* stats = (float2*)(smem + 65536);    // [64 rows][8 waves] (S, S2)

  const int tid = threadIdx.x;
  const int wv = tid >> 6, lane = tid & 63;
  const int q = lane >> 4, m = lane & 15;
  const int row0 = blockIdx.x * 64;
  const int wb = wv * 4;                      // wave's n-tile base (of 32 tiles)

  // loop-invariant per-lane indices
  int hoff[4], n0[4];
#pragma unroll
  for (int ntl = 0; ntl < 4; ++ntl) {
    int ntg = wb + ntl;
    int kcn = ntg >> 1, hs = ntg & 1;
    int qp = hs * 2 + (q >> 1), j0 = (q & 1) * 4;
    hoff[ntl] = ((kcn * 4) * 64 + qp * 16 + m) * 8 + j0;   // + bt*512
    n0[ntl] = ntg * 16 + q * 4;
  }

  // ---- stage x into hb fragment order (kc < 8, K=256)
  {
    const float4* x4 = (const float4*)P.x;
#pragma unroll
    for (int i = 0; i < 4; ++i) {
      int f = i * 512 + tid;              // 0..2047
      int lf = f & 63, rest = f >> 6;     // rest 0..31
      int bt = rest & 3, kc = rest >> 2;
      int qf = lf >> 4, mf = lf & 15;
      int row = row0 + bt * 16 + mf;
      int c4 = kc * 8 + qf * 2;
      float4 v0 = x4[(size_t)row * 64 + c4];
      float4 v1 = x4[(size_t)row * 64 + c4 + 1];
      uint4 o;
      o.x = pk2(v0.x, v0.y); o.y = pk2(v0.z, v0.w);
      o.z = pk2(v1.x, v1.y); o.w = pk2(v1.z, v1.w);
      *(uint4*)(hb + (size_t)f * 8) = o;
    }
  }
  __syncthreads();

  v4f acc[4][4];       // [ntl][bt] GEMM accum (C layout), recycled as h_new
  uint2 basep[4][4];   // base' = -log2e*(i_input + bias), packed bf16

#pragma unroll 1
  for (int l = 0; l < 3; ++l) {
    const LayerG L = P.L[l];

    // ---- i_input' GEMM (win pre-scaled by -log2e) + base pack
    if (l == 0) gemmA<8>(hb, L.win, wb, lane, acc);
    else        gemmA<16>(hb, L.win, wb, lane, acc);
#pragma unroll
    for (int ntl = 0; ntl < 4; ++ntl) {
      float4 b4 = *(const float4*)(L.bias + n0[ntl]);
      float bs[4] = {b4.x * NLOG2E, b4.y * NLOG2E, b4.z * NLOG2E, b4.w * NLOG2E};
#pragma unroll
      for (int bt = 0; bt < 4; ++bt) {
        basep[ntl][bt].x = pk2(acc[ntl][bt][0] + bs[0], acc[ntl][bt][1] + bs[1]);
        basep[ntl][bt].y = pk2(acc[ntl][bt][2] + bs[2], acc[ntl][bt][3] + bs[3]);
      }
    }

#pragma unroll 1
    for (int s = 0; s < NSTEPS; ++s) {
      if (s > 0) gemmA<16>(hb, L.wrec, wb, lane, acc);   // h @ (W_rec*mask)'

      // ---- pass 1: sigmoid + semi-implicit update (in C layout = A order), stats
      float S[4] = {0.f, 0.f, 0.f, 0.f}, S2[4] = {0.f, 0.f, 0.f, 0.f};
#pragma unroll
      for (int ntl = 0; ntl < 4; ++ntl) {
        float4 a4 = *(const float4*)(L.cA + n0[ntl]);
        float4 c4 = *(const float4*)(L.cC1 + n0[ntl]);
        float av[4] = {a4.x, a4.y, a4.z, a4.w};
        float cv[4] = {c4.x, c4.y, c4.z, c4.w};
#pragma unroll
        for (int bt = 0; bt < 4; ++bt) {
          uint2 hh = make_uint2(0u, 0u);
          if (s > 0) hh = *(const uint2*)(hb + hoff[ntl] + bt * 512);
          unsigned blo = basep[ntl][bt].x, bhi = basep[ntl][bt].y;
#pragma unroll
          for (int r = 0; r < 4; ++r) {
            float bv = (r == 0) ? bfl(blo) : (r == 1) ? bfh(blo)
                     : (r == 2) ? bfl(bhi) : bfh(bhi);
            float arg = (s > 0) ? acc[ntl][bt][r] + bv : bv;
            float hv = 0.f;
            if (s > 0)
              hv = (r == 0) ? bfl(hh.x) : (r == 1) ? bfh(hh.x)
                 : (r == 2) ? bfl(hh.y) : bfh(hh.y);
            float e = exp2f(arg);                    // = exp(-(i+hW+bias))
            float num = fmaf(hv, e, hv + av[r]);     // Mobius x(1+e)
            float den = fmaf(cv[r], e, cv[r] + DT);
            float hn = num * __builtin_amdgcn_rcpf(den);
            S[bt] += hn;
            S2[bt] = fmaf(hn, hn, S2[bt]);
            acc[ntl][bt][r] = hn;
          }
        }
      }
#pragma unroll
      for (int bt = 0; bt < 4; ++bt) {
        S[bt]  += __shfl_xor(S[bt], 16);  S[bt]  += __shfl_xor(S[bt], 32);
        S2[bt] += __shfl_xor(S2[bt], 16); S2[bt] += __shfl_xor(S2[bt], 32);
      }
      if (q == 0) {
#pragma unroll
        for (int bt = 0; bt < 4; ++bt)
          stats[(bt * 16 + m) * 8 + wv] = make_float2(S[bt], S2[bt]);
      }
      __syncthreads();   // bar1: stats visible; all hb reads of this step done

      // ---- redundant per-lane stats finalize (broadcast LDS reads)
      float rsv[4], nmv[4];
#pragma unroll
      for (int bt = 0; bt < 4; ++bt) {
        const float4* sp = (const float4*)(stats + (bt * 16 + m) * 8);
        float4 p0 = sp[0], p1 = sp[1], p2 = sp[2], p3 = sp[3];
        float Sa = ((p0.x + p0.z) + (p1.x + p1.z)) + ((p2.x + p2.z) + (p3.x + p3.z));
        float Sb = ((p0.y + p0.w) + (p1.y + p1.w)) + ((p2.y + p2.w) + (p3.y + p3.w));
        float mu = Sa * (1.f / 512.f);
        float var = fmaf(-mu, mu, Sb * (1.f / 512.f));
        float rs = __builtin_amdgcn_rsqf(var + LNEPS);
        rsv[bt] = rs;
        nmv[bt] = -mu * rs;
      }

      // ---- pass 2: normalize + affine, contiguous b64 writes in place
#pragma unroll
      for (int ntl = 0; ntl < 4; ++ntl) {
        float4 g4 = *(const float4*)(L.cG + n0[ntl]);
        float4 b4 = *(const float4*)(L.cB + n0[ntl]);
        float gv[4] = {g4.x, g4.y, g4.z, g4.w};
        float bv[4] = {b4.x, b4.y, b4.z, b4.w};
#pragma unroll
        for (int bt = 0; bt < 4; ++bt) {
          float v0 = fmaf(fmaf(acc[ntl][bt][0], rsv[bt], nmv[bt]), gv[0], bv[0]);
          float v1 = fmaf(fmaf(acc[ntl][bt][1], rsv[bt], nmv[bt]), gv[1], bv[1]);
          float v2 = fmaf(fmaf(acc[ntl][bt][2], rsv[bt], nmv[bt]), gv[2], bv[2]);
          float v3 = fmaf(fmaf(acc[ntl][bt][3], rsv[bt], nmv[bt]), gv[3], bv[3]);
          uint2 o;
          o.x = pk2(v0, v1);
          o.y = pk2(v2, v3);
          *(uint2*)(hb + hoff[ntl] + bt * 512) = o;
        }
      }
      __syncthreads();   // bar2: h_new visible for next GEMM
    }
  }

  // ---- output projection: D = out_W · h^T (O=128; wave owns o-tile wv)
  v4f oa[4];
#pragma unroll
  for (int bt = 0; bt < 4; ++bt) oa[bt] = (v4f){0.f, 0.f, 0.f, 0.f};
#pragma unroll
  for (int kc = 0; kc < 16; ++kc) {
    v8s a = *(const v8s*)(P.wout + ((size_t)(kc * 8 + wv) * 64 + lane) * 8);
#pragma unroll
    for (int bt = 0; bt < 4; ++bt) {
      v8s b = *(const v8s*)(hb + ((size_t)(kc * 4 + bt) * 64 + lane) * 8);
      oa[bt] = __builtin_amdgcn_mfma_f32_16x16x32_bf16(a, b, oa[bt], 0, 0, 0);
    }
  }
  {
    float4 ob = *(const float4*)(P.outb + wv * 16 + q * 4);
#pragma unroll
    for (int bt = 0; bt < 4; ++bt) {
      float4 o;
      o.x = oa[bt][0] + ob.x;
      o.y = oa[bt][1] + ob.y;
      o.z = oa[bt][2] + ob.z;
      o.w = oa[bt][3] + ob.w;
      *(float4*)(P.out + (size_t)(row0 + bt * 16 + m) * 128 + wv * 16 + q * 4) = o;
    }
  }
}

// ---------------------------------------------------------------------------
extern "C" void kernel_launch(void* const* d_in, const int* in_sizes, int n_in,
                              void* d_out, int out_size, void* d_ws, size_t ws_size,
                              hipStream_t stream) {
  (void)in_sizes; (void)n_in; (void)out_size; (void)ws_size;
  ushort* ws = (ushort*)d_ws;

  const size_t S_WIN0 = 0;                                  //  8*32*64*8
  const size_t S_WIN1 = S_WIN0 + (size_t)8 * 32 * 64 * 8;
  const size_t S_WIN2 = S_WIN1 + (size_t)16 * 32 * 64 * 8;
  const size_t S_REC0 = S_WIN2 + (size_t)16 * 32 * 64 * 8;
  const size_t S_REC1 = S_REC0 + (size_t)16 * 32 * 64 * 8;
  const size_t S_REC2 = S_REC1 + (size_t)16 * 32 * 64 * 8;
  const size_t S_WOUT = S_REC2 + (size_t)16 * 32 * 64 * 8;
  const size_t CONST_B = (S_WOUT + (size_t)16 * 8 * 64 * 8) * 2;  // byte offset

  const float* f[27];
  for (int i = 0; i < 27; ++i) f[i] = (const float*)d_in[i];

  dim3 bt(256);
  // W_in: A[n][k] = W_in[k][n] (indirect); W_rec/out_W: direct row-major.
  pack_wA<<<dim3(64),  bt, 0, stream>>>(f[1],  nullptr, ws + S_WIN0, 256, 512, 0, NLOG2E);
  pack_wA<<<dim3(128), bt, 0, stream>>>(f[9],  nullptr, ws + S_WIN1, 512, 512, 0, NLOG2E);
  pack_wA<<<dim3(128), bt, 0, stream>>>(f[17], nullptr, ws + S_WIN2, 512, 512, 0, NLOG2E);
  pack_wA<<<dim3(128), bt, 0, stream>>>(f[2],  f[6],    ws + S_REC0, 512, 512, 1, NLOG2E);
  pack_wA<<<dim3(128), bt, 0, stream>>>(f[10], f[14],   ws + S_REC1, 512, 512, 1, NLOG2E);
  pack_wA<<<dim3(128), bt, 0, stream>>>(f[18], f[22],   ws + S_REC2, 512, 512, 1, NLOG2E);
  pack_wA<<<dim3(32),  bt, 0, stream>>>(f[25], nullptr, ws + S_WOUT, 512, 128, 1, 1.0f);

  float* cbase = (float*)((char*)d_ws + CONST_B);   // 4 planar arrays x 3 layers
  for (int l = 0; l < 3; ++l) {
    int b0 = 1 + 8 * l;
    float* c = cbase + (size_t)l * 4 * 512;
    pack_consts<<<dim3(2), bt, 0, stream>>>(f[b0 + 3], f[b0 + 4], f[b0 + 6], f[b0 + 7],
                                            c, c + 512, c + 1024, c + 1536);
  }

  KP P;
  P.x = f[0];
  const size_t win_off[3] = {S_WIN0, S_WIN1, S_WIN2};
  const size_t rec_off[3] = {S_REC0, S_REC1, S_REC2};
  for (int l = 0; l < 3; ++l) {
    int b0 = 1 + 8 * l;
    float* c = cbase + (size_t)l * 4 * 512;
    P.L[l].win  = ws + win_off[l];
    P.L[l].wrec = ws + rec_off[l];
    P.L[l].bias = f[b0 + 2];
    P.L[l].cA   = c;
    P.L[l].cC1  = c + 512;
    P.L[l].cG   = c + 1024;
    P.L[l].cB   = c + 1536;
  }
  P.wout = ws + S_WOUT;
  P.outb = f[26];
  P.out  = (float*)d_out;

  const int smem = 65536 + 64 * 8 * 8;   // hb 64 KB + stats 4 KB = 69632 B
  hipFuncSetAttribute((const void*)liquid_fused,
                      hipFuncAttributeMaxDynamicSharedMemorySize, smem);
  liquid_fused<<<dim3(512), dim3(512), smem, stream>>>(P);
}

// Round 5
// 1673.235 us; speedup vs baseline: 1.4725x; 1.4725x over previous
//
#include <hip/hip_runtime.h>
#include <hip/hip_bf16.h>

#define NSTEPS 10
#define DT     0.1f
#define LNEPS  1e-5f
#define NLOG2E (-1.4426950408889634f)

typedef __attribute__((ext_vector_type(8))) short v8s;   // 8 bf16 MFMA operand
typedef __attribute__((ext_vector_type(4))) float v4f;   // 4 fp32 MFMA accum

static __device__ __forceinline__ ushort f2bf(float f) {
  union { float f; unsigned u; } v; v.f = f;
  unsigned r = v.u + 0x7fffu + ((v.u >> 16) & 1u);   // RNE
  return (ushort)(r >> 16);
}
static __device__ __forceinline__ float bfl(unsigned u) {
  union { unsigned x; float f; } c; c.x = u << 16; return c.f;
}
static __device__ __forceinline__ float bfh(unsigned u) {
  union { unsigned x; float f; } c; c.x = u & 0xffff0000u; return c.f;
}
static __device__ __forceinline__ unsigned pk2(float a, float b) {
  union { __hip_bfloat162 h; unsigned u; } c;
  c.h = __float22bfloat162_rn(make_float2(a, b));   // v_cvt_pk_bf16_f32
  return c.u;
}

// ---------------------------------------------------------------------------
// Pack W into MFMA A-fragment order (operand-swapped GEMM: D = W · h^T).
// A[i][k]: frag f = (kc*NT + nt)*64 + lane; lane=(q,m): value = W_A[nt*16+m][kc*32+q*8+j].
// direct==1: W_A[n][k] = src[n*K + k] (*msk)   (W_rec masked, out_W)
// direct==0: W_A[n][k] = src[k*N + n]          (W_in)
// ---------------------------------------------------------------------------
__global__ void pack_wA(const float* __restrict__ src, const float* __restrict__ msk,
                        ushort* __restrict__ dst, int K, int N, int direct, float scale) {
  int ntc = N >> 4;
  int tot = (K >> 5) * ntc * 64;
  int f = blockIdx.x * blockDim.x + threadIdx.x;
  if (f >= tot) return;
  int lf = f & 63;
  int rest = f >> 6;
  int nt = rest % ntc;
  int kc = rest / ntc;
  int n = nt * 16 + (lf & 15);
  int kb = kc * 32 + (lf >> 4) * 8;
  ushort v[8];
#pragma unroll
  for (int j = 0; j < 8; ++j) {
    int k = kb + j;
    float s;
    if (direct) {
      s = src[(size_t)n * K + k];
      if (msk) s *= msk[(size_t)n * K + k];
    } else {
      s = src[(size_t)k * N + n];
    }
    v[j] = f2bf(s * scale);
  }
  uint4 u;
  u.x = (unsigned)v[0] | ((unsigned)v[1] << 16);
  u.y = (unsigned)v[2] | ((unsigned)v[3] << 16);
  u.z = (unsigned)v[4] | ((unsigned)v[5] << 16);
  u.w = (unsigned)v[6] | ((unsigned)v[7] << 16);
  *(uint4*)(dst + (size_t)f * 8) = u;
}

// Planar per-col constants: cA = dt*A, cC1 = 1+dt/tau, cG = g, cB = b.
__global__ void pack_consts(const float* __restrict__ tau, const float* __restrict__ A,
                            const float* __restrict__ g, const float* __restrict__ b,
                            float* __restrict__ cA, float* __restrict__ cC1,
                            float* __restrict__ cG, float* __restrict__ cB) {
  int c = blockIdx.x * blockDim.x + threadIdx.x;
  if (c >= 512) return;
  cA[c] = DT * A[c];
  cC1[c] = 1.f + DT / tau[c];
  cG[c] = g[c];
  cB[c] = b[c];
}

struct LayerG {
  const ushort* win;
  const ushort* wrec;
  const float*  bias;   // raw f32, scaled by -log2e at base build
  const float*  cA, *cC1, *cG, *cB;
};
struct KP {
  const float* x;
  LayerG L[3];
  const ushort* wout;
  const float*  outb;
  float* out;
};

// ---------------------------------------------------------------------------
// Operand-swapped GEMM: acc[nt][bt] = W_slab · h^T.
// A (weights) streamed from global (L2), 2-deep prefetch.
// B (h) read from fragment-ordered LDS: lane-contiguous ds_read_b128.
// D C-layout: n = (wv*4+nt)*16 + q*4 + r,  batchrow = bt*16 + m.
// ---------------------------------------------------------------------------
template <int KC>
static __device__ __forceinline__ void gemmA(const ushort* hb, const ushort* __restrict__ w,
                                             int wb, int lane, v4f (&acc)[4][4]) {
#pragma unroll
  for (int nt = 0; nt < 4; ++nt)
#pragma unroll
    for (int bt = 0; bt < 4; ++bt) acc[nt][bt] = (v4f){0.f, 0.f, 0.f, 0.f};
  v8s a0[4], a1[4];
  auto ldA = [&](v8s (&a)[4], int kc) {
#pragma unroll
    for (int nt = 0; nt < 4; ++nt)
      a[nt] = *(const v8s*)(w + ((size_t)(kc * 32 + wb + nt) * 64 + lane) * 8);
  };
  auto body = [&](v8s (&a)[4], int kc) {
    v8s b[4];
#pragma unroll
    for (int bt = 0; bt < 4; ++bt)
      b[bt] = *(const v8s*)(hb + ((size_t)(kc * 4 + bt) * 64 + lane) * 8);
#pragma unroll
    for (int nt = 0; nt < 4; ++nt)
#pragma unroll
      for (int bt = 0; bt < 4; ++bt)
        acc[nt][bt] = __builtin_amdgcn_mfma_f32_16x16x32_bf16(a[nt], b[bt], acc[nt][bt], 0, 0, 0);
    if (kc + 2 < KC) ldA(a, kc + 2);
  };
  ldA(a0, 0);
  ldA(a1, 1);
#pragma unroll
  for (int kc = 0; kc < KC; kc += 2) {
    body(a0, kc);
    body(a1, kc + 1);
  }
}

// ---------------------------------------------------------------------------
// Fused kernel: 512 thr (8 waves), 64 rows/block, grid 512 (2 rounds/CU).
// h AND base live in LDS in B-fragment order; 2 barriers/step; no transposes;
// nothing but acc + prefetch regs live across the GEMM (no spill).
// ---------------------------------------------------------------------------
__global__ __launch_bounds__(512, 1) void liquid_fused(KP P) {
  extern __shared__ char smem[];
  ushort* hb = (ushort*)smem;                  // 16kc x 4bt x 64lane x 8 = 64 KB
  ushort* bb = hb + 32768;                     // base', same layout, 64 KB
  float2* stats = (float2*)(smem + 131072);    // [64 rows][stride 10] (S, S2)

  const int tid = threadIdx.x;
  const int wv = tid >> 6, lane = tid & 63;
  const int q = lane >> 4, m = lane & 15;
  const int row0 = blockIdx.x * 64;
  const int wb = wv * 4;                       // wave's n-tile base (of 32 tiles)

  // loop-invariant per-lane indices
  int hoff[4], n0[4];
#pragma unroll
  for (int ntl = 0; ntl < 4; ++ntl) {
    int ntg = wb + ntl;
    int kcn = ntg >> 1, hs = ntg & 1;
    int qp = hs * 2 + (q >> 1), j0 = (q & 1) * 4;
    hoff[ntl] = ((kcn * 4) * 64 + qp * 16 + m) * 8 + j0;   // + bt*512
    n0[ntl] = ntg * 16 + q * 4;
  }

  // ---- stage x into hb fragment order (kc < 8, K=256)
  {
    const float4* x4 = (const float4*)P.x;
#pragma unroll
    for (int i = 0; i < 4; ++i) {
      int f = i * 512 + tid;              // 0..2047
      int lf = f & 63, rest = f >> 6;     // rest 0..31
      int bt = rest & 3, kc = rest >> 2;
      int qf = lf >> 4, mf = lf & 15;
      int row = row0 + bt * 16 + mf;
      int c4 = kc * 8 + qf * 2;
      float4 v0 = x4[(size_t)row * 64 + c4];
      float4 v1 = x4[(size_t)row * 64 + c4 + 1];
      uint4 o;
      o.x = pk2(v0.x, v0.y); o.y = pk2(v0.z, v0.w);
      o.z = pk2(v1.x, v1.y); o.w = pk2(v1.z, v1.w);
      *(uint4*)(hb + (size_t)f * 8) = o;
    }
  }
  __syncthreads();

  v4f acc[4][4];       // [ntl][bt] GEMM accum (C layout), recycled as h_new

#pragma unroll 1
  for (int l = 0; l < 3; ++l) {
    const LayerG L = P.L[l];

    // ---- hoisted per-layer epilogue constants (n-indexed, 80 VGPRs)
    float av[4][4], cv[4][4], cvd[4][4], gg[4][4], gb[4][4];
#pragma unroll
    for (int ntl = 0; ntl < 4; ++ntl) {
      float4 a4 = *(const float4*)(L.cA + n0[ntl]);
      float4 c4 = *(const float4*)(L.cC1 + n0[ntl]);
      float4 g4 = *(const float4*)(L.cG + n0[ntl]);
      float4 b4 = *(const float4*)(L.cB + n0[ntl]);
#pragma unroll
      for (int r = 0; r < 4; ++r) {
        av[ntl][r] = ((const float*)&a4)[r];
        cv[ntl][r] = ((const float*)&c4)[r];
        cvd[ntl][r] = ((const float*)&c4)[r] + DT;
        gg[ntl][r] = ((const float*)&g4)[r];
        gb[ntl][r] = ((const float*)&b4)[r];
      }
    }

    // ---- i_input' GEMM (win pre-scaled by -log2e); base' -> bb (LDS, bf16)
    if (l == 0) gemmA<8>(hb, L.win, wb, lane, acc);
    else        gemmA<16>(hb, L.win, wb, lane, acc);
#pragma unroll
    for (int ntl = 0; ntl < 4; ++ntl) {
      float4 b4 = *(const float4*)(L.bias + n0[ntl]);
      float bs[4] = {b4.x * NLOG2E, b4.y * NLOG2E, b4.z * NLOG2E, b4.w * NLOG2E};
#pragma unroll
      for (int bt = 0; bt < 4; ++bt) {
        uint2 o;
        o.x = pk2(acc[ntl][bt][0] + bs[0], acc[ntl][bt][1] + bs[1]);
        o.y = pk2(acc[ntl][bt][2] + bs[2], acc[ntl][bt][3] + bs[3]);
        *(uint2*)(bb + hoff[ntl] + bt * 512) = o;   // same-lane write/read: no barrier
      }
    }

#pragma unroll 1
    for (int s = 0; s < NSTEPS; ++s) {
      if (s > 0) gemmA<16>(hb, L.wrec, wb, lane, acc);   // h @ (W_rec*mask)'

      // ---- pass 1: sigmoid + semi-implicit update (C layout), stats
      float S[4] = {0.f, 0.f, 0.f, 0.f}, S2[4] = {0.f, 0.f, 0.f, 0.f};
#pragma unroll
      for (int ntl = 0; ntl < 4; ++ntl) {
#pragma unroll
        for (int bt = 0; bt < 4; ++bt) {
          uint2 bd = *(const uint2*)(bb + hoff[ntl] + bt * 512);
          uint2 hh = make_uint2(0u, 0u);
          if (s > 0) hh = *(const uint2*)(hb + hoff[ntl] + bt * 512);
#pragma unroll
          for (int r = 0; r < 4; ++r) {
            float bv = (r == 0) ? bfl(bd.x) : (r == 1) ? bfh(bd.x)
                     : (r == 2) ? bfl(bd.y) : bfh(bd.y);
            float arg = (s > 0) ? acc[ntl][bt][r] + bv : bv;
            float hv = 0.f;
            if (s > 0)
              hv = (r == 0) ? bfl(hh.x) : (r == 1) ? bfh(hh.x)
                 : (r == 2) ? bfl(hh.y) : bfh(hh.y);
            float e = exp2f(arg);                       // = exp(-(i+hW+bias))
            float num = fmaf(hv, e, hv + av[ntl][r]);   // Mobius x(1+e)
            float den = fmaf(cv[ntl][r], e, cvd[ntl][r]);
            float hn = num * __builtin_amdgcn_rcpf(den);
            S[bt] += hn;
            S2[bt] = fmaf(hn, hn, S2[bt]);
            acc[ntl][bt][r] = hn;
          }
        }
      }
#pragma unroll
      for (int bt = 0; bt < 4; ++bt) {
        S[bt]  += __shfl_xor(S[bt], 16);  S[bt]  += __shfl_xor(S[bt], 32);
        S2[bt] += __shfl_xor(S2[bt], 16); S2[bt] += __shfl_xor(S2[bt], 32);
      }
      if (q == 0) {
#pragma unroll
        for (int bt = 0; bt < 4; ++bt)
          stats[(bt * 16 + m) * 10 + wv] = make_float2(S[bt], S2[bt]);
      }
      __syncthreads();   // bar1: stats visible; all hb reads of this step done

      // ---- redundant per-lane stats finalize (stride-10 rows: conflict-free)
      float rsv[4], nmv[4];
#pragma unroll
      for (int bt = 0; bt < 4; ++bt) {
        const float4* sp = (const float4*)(stats + (bt * 16 + m) * 10);
        float4 p0 = sp[0], p1 = sp[1], p2 = sp[2], p3 = sp[3];
        float Sa = ((p0.x + p0.z) + (p1.x + p1.z)) + ((p2.x + p2.z) + (p3.x + p3.z));
        float Sb = ((p0.y + p0.w) + (p1.y + p1.w)) + ((p2.y + p2.w) + (p3.y + p3.w));
        float mu = Sa * (1.f / 512.f);
        float var = fmaf(-mu, mu, Sb * (1.f / 512.f));
        float rs = __builtin_amdgcn_rsqf(var + LNEPS);
        rsv[bt] = rs;
        nmv[bt] = -mu * rs;
      }

      // ---- pass 2: normalize + affine, contiguous b64 writes in place
#pragma unroll
      for (int ntl = 0; ntl < 4; ++ntl) {
#pragma unroll
        for (int bt = 0; bt < 4; ++bt) {
          float v0 = fmaf(fmaf(acc[ntl][bt][0], rsv[bt], nmv[bt]), gg[ntl][0], gb[ntl][0]);
          float v1 = fmaf(fmaf(acc[ntl][bt][1], rsv[bt], nmv[bt]), gg[ntl][1], gb[ntl][1]);
          float v2 = fmaf(fmaf(acc[ntl][bt][2], rsv[bt], nmv[bt]), gg[ntl][2], gb[ntl][2]);
          float v3 = fmaf(fmaf(acc[ntl][bt][3], rsv[bt], nmv[bt]), gg[ntl][3], gb[ntl][3]);
          uint2 o;
          o.x = pk2(v0, v1);
          o.y = pk2(v2, v3);
          *(uint2*)(hb + hoff[ntl] + bt * 512) = o;
        }
      }
      __syncthreads();   // bar2: h_new visible for next GEMM
    }
  }

  // ---- output projection: D = out_W · h^T (O=128; wave owns o-tile wv)
  v4f oa[4];
#pragma unroll
  for (int bt = 0; bt < 4; ++bt) oa[bt] = (v4f){0.f, 0.f, 0.f, 0.f};
#pragma unroll
  for (int kc = 0; kc < 16; ++kc) {
    v8s a = *(const v8s*)(P.wout + ((size_t)(kc * 8 + wv) * 64 + lane) * 8);
#pragma unroll
    for (int bt = 0; bt < 4; ++bt) {
      v8s b = *(const v8s*)(hb + ((size_t)(kc * 4 + bt) * 64 + lane) * 8);
      oa[bt] = __builtin_amdgcn_mfma_f32_16x16x32_bf16(a, b, oa[bt], 0, 0, 0);
    }
  }
  {
    float4 ob = *(const float4*)(P.outb + wv * 16 + q * 4);
#pragma unroll
    for (int bt = 0; bt < 4; ++bt) {
      float4 o;
      o.x = oa[bt][0] + ob.x;
      o.y = oa[bt][1] + ob.y;
      o.z = oa[bt][2] + ob.z;
      o.w = oa[bt][3] + ob.w;
      *(float4*)(P.out + (size_t)(row0 + bt * 16 + m) * 128 + wv * 16 + q * 4) = o;
    }
  }
}

// ---------------------------------------------------------------------------
extern "C" void kernel_launch(void* const* d_in, const int* in_sizes, int n_in,
                              void* d_out, int out_size, void* d_ws, size_t ws_size,
                              hipStream_t stream) {
  (void)in_sizes; (void)n_in; (void)out_size; (void)ws_size;
  ushort* ws = (ushort*)d_ws;

  const size_t S_WIN0 = 0;                                  //  8*32*64*8
  const size_t S_WIN1 = S_WIN0 + (size_t)8 * 32 * 64 * 8;
  const size_t S_WIN2 = S_WIN1 + (size_t)16 * 32 * 64 * 8;
  const size_t S_REC0 = S_WIN2 + (size_t)16 * 32 * 64 * 8;
  const size_t S_REC1 = S_REC0 + (size_t)16 * 32 * 64 * 8;
  const size_t S_REC2 = S_REC1 + (size_t)16 * 32 * 64 * 8;
  const size_t S_WOUT = S_REC2 + (size_t)16 * 32 * 64 * 8;
  const size_t CONST_B = (S_WOUT + (size_t)16 * 8 * 64 * 8) * 2;  // byte offset

  const float* f[27];
  for (int i = 0; i < 27; ++i) f[i] = (const float*)d_in[i];

  dim3 bt(256);
  // W_in: A[n][k] = W_in[k][n] (indirect); W_rec/out_W: direct row-major.
  pack_wA<<<dim3(64),  bt, 0, stream>>>(f[1],  nullptr, ws + S_WIN0, 256, 512, 0, NLOG2E);
  pack_wA<<<dim3(128), bt, 0, stream>>>(f[9],  nullptr, ws + S_WIN1, 512, 512, 0, NLOG2E);
  pack_wA<<<dim3(128), bt, 0, stream>>>(f[17], nullptr, ws + S_WIN2, 512, 512, 0, NLOG2E);
  pack_wA<<<dim3(128), bt, 0, stream>>>(f[2],  f[6],    ws + S_REC0, 512, 512, 1, NLOG2E);
  pack_wA<<<dim3(128), bt, 0, stream>>>(f[10], f[14],   ws + S_REC1, 512, 512, 1, NLOG2E);
  pack_wA<<<dim3(128), bt, 0, stream>>>(f[18], f[22],   ws + S_REC2, 512, 512, 1, NLOG2E);
  pack_wA<<<dim3(32),  bt, 0, stream>>>(f[25], nullptr, ws + S_WOUT, 512, 128, 1, 1.0f);

  float* cbase = (float*)((char*)d_ws + CONST_B);   // 4 planar arrays x 3 layers
  for (int l = 0; l < 3; ++l) {
    int b0 = 1 + 8 * l;
    float* c = cbase + (size_t)l * 4 * 512;
    pack_consts<<<dim3(2), bt, 0, stream>>>(f[b0 + 3], f[b0 + 4], f[b0 + 6], f[b0 + 7],
                                            c, c + 512, c + 1024, c + 1536);
  }

  KP P;
  P.x = f[0];
  const size_t win_off[3] = {S_WIN0, S_WIN1, S_WIN2};
  const size_t rec_off[3] = {S_REC0, S_REC1, S_REC2};
  for (int l = 0; l < 3; ++l) {
    int b0 = 1 + 8 * l;
    float* c = cbase + (size_t)l * 4 * 512;
    P.L[l].win  = ws + win_off[l];
    P.L[l].wrec = ws + rec_off[l];
    P.L[l].bias = f[b0 + 2];
    P.L[l].cA   = c;
    P.L[l].cC1  = c + 512;
    P.L[l].cG   = c + 1024;
    P.L[l].cB   = c + 1536;
  }
  P.wout = ws + S_WOUT;
  P.outb = f[26];
  P.out  = (float*)d_out;

  const int smem = 131072 + 64 * 10 * 8;   // hb 64K + bb 64K + stats 5K = 136192 B
  hipFuncSetAttribute((const void*)liquid_fused,
                      hipFuncAttributeMaxDynamicSharedMemorySize, smem);
  liquid_fused<<<dim3(512), dim3(512), smem, stream>>>(P);
}